// Round 3
// baseline (672.595 us; speedup 1.0000x reference)
//
#include <hip/hip_runtime.h>

#define Bv 64
#define Tv 2048
#define Hv 1024
#define Uv 128
#define Mv 512

typedef __bf16 bf16x8 __attribute__((ext_vector_type(8)));
typedef float f32x4 __attribute__((ext_vector_type(4)));
union U4BF { uint4 u; bf16x8 b; };
#define MFMA(a, b, c) __builtin_amdgcn_mfma_f32_16x16x32_bf16((a), (b), (c), 0, 0, 0)

__device__ __forceinline__ unsigned short f2bf(float f) {
  __bf16 h = (__bf16)f;
  return __builtin_bit_cast(unsigned short, h);
}
__device__ __forceinline__ unsigned int pack2(unsigned short lo, unsigned short hi) {
  return (unsigned int)lo | ((unsigned int)hi << 16);
}
__device__ __forceinline__ float fast_tanh(float x) {
  x = fminf(fmaxf(x, -15.0f), 15.0f);
  float e = __expf(2.0f * x);
  return (e - 1.0f) / (e + 1.0f);
}

// ================= prep: one launch does everything =================
// bx in [0,64):   qe[b,n] = (query[b]@Wq + bq + bias2 + bm)@We + be
// bx == 64:       W2 = conv-fold(Wl), W3 = W2@We, pack W3F
// bx in [65,97):  pack WmF (4 frags/block)
// bx in [97,105): pack WeF (4 frags/block)
// bx in [105,114): zero P0/P1/Ssg/cnt (first 16512 floats of ws)
__global__ __launch_bounds__(256) void prep_kernel(
    const float* __restrict__ query, const float* __restrict__ Wq,
    const float* __restrict__ bq, const float* __restrict__ Wl,
    const float* __restrict__ bl, const float* __restrict__ conv_w,
    const float* __restrict__ conv_b, const float* __restrict__ bm,
    const float* __restrict__ be, const float* __restrict__ We,
    const float* __restrict__ Wm,
    float* __restrict__ qe, unsigned short* __restrict__ W3F,
    unsigned short* __restrict__ WmF, unsigned short* __restrict__ WeF,
    float* __restrict__ zeroRegion) {
  const int bx = blockIdx.x, tid = threadIdx.x;
  if (bx < 64) {
    const int b = bx;
    __shared__ float part[256];
    __shared__ float svec[128];
    const int u = tid & 127, half = tid >> 7;
    float acc = 0.0f;
    const float* q  = query + b * Hv + half * 512;
    const float* wq = Wq + (size_t)(half * 512) * Uv + u;
    for (int h = 0; h < 512; ++h) acc = fmaf(q[h], wq[(size_t)h * Uv], acc);
    part[tid] = acc;
    __syncthreads();
    if (tid < 128) {
      float pq = part[tid] + part[tid + 128] + bq[tid];
      float b2 = bl[tid];
      #pragma unroll
      for (int f = 0; f < 32; ++f) b2 = fmaf(conv_b[f], Wl[f * Uv + tid], b2);
      svec[tid] = pq + b2 + bm[tid];
    }
    __syncthreads();
    const int n = tid & 127;
    float acc2 = 0.0f;
    const float* we = We + (size_t)(half * 64) * Uv + n;
    for (int uu = 0; uu < 64; ++uu) acc2 = fmaf(svec[half * 64 + uu], we[(size_t)uu * Uv], acc2);
    part[tid] = acc2;
    __syncthreads();
    if (tid < 128) qe[b * Uv + tid] = part[tid] + part[tid + 128] + be[tid];
  } else if (bx == 64) {
    __shared__ float sW2[31 * 128];
    __shared__ float sW3[32 * 128];
    for (int idx = tid; idx < 31 * 128; idx += 256) {
      int k = idx >> 7, uu = idx & 127;
      float a = 0.0f;
      #pragma unroll
      for (int f = 0; f < 32; ++f) a = fmaf(conv_w[f * 31 + k], Wl[f * Uv + uu], a);
      sW2[idx] = a;
    }
    __syncthreads();
    for (int idx = tid; idx < 32 * 128; idx += 256) {
      int k = idx >> 7, n = idx & 127;
      float a = 0.0f;
      if (k < 31) {
        for (int uu = 0; uu < 128; ++uu) a = fmaf(sW2[k * 128 + uu], We[(size_t)uu * Uv + n], a);
      }
      sW3[idx] = a;
    }
    __syncthreads();
    for (int s = tid; s < 512; s += 256) {
      int nj = s >> 6, lane = s & 63, quad = lane >> 4, l4 = lane & 15;
      float v[8];
      #pragma unroll
      for (int j = 0; j < 8; ++j) v[j] = sW3[(quad * 8 + j) * 128 + nj * 16 + l4];
      uint4 o;
      o.x = pack2(f2bf(v[0]), f2bf(v[1])); o.y = pack2(f2bf(v[2]), f2bf(v[3]));
      o.z = pack2(f2bf(v[4]), f2bf(v[5])); o.w = pack2(f2bf(v[6]), f2bf(v[7]));
      *(uint4*)(W3F + (size_t)nj * 512 + lane * 8) = o;
    }
  } else if (bx < 97) {
    const int fid = (bx - 65) * 4 + (tid >> 6);
    const int lane = tid & 63, quad = lane >> 4, l4 = lane & 15;
    const int kc = fid >> 3, uj = fid & 7;
    float v[8];
    #pragma unroll
    for (int j = 0; j < 8; ++j) v[j] = Wm[(size_t)(kc * 32 + quad * 8 + j) * Uv + uj * 16 + l4];
    uint4 o;
    o.x = pack2(f2bf(v[0]), f2bf(v[1])); o.y = pack2(f2bf(v[2]), f2bf(v[3]));
    o.z = pack2(f2bf(v[4]), f2bf(v[5])); o.w = pack2(f2bf(v[6]), f2bf(v[7]));
    *(uint4*)(WmF + (size_t)fid * 512 + lane * 8) = o;
  } else if (bx < 105) {
    const int f2 = (bx - 97) * 4 + (tid >> 6);
    const int lane = tid & 63, quad = lane >> 4, l4 = lane & 15;
    const int ks = f2 >> 3, nj = f2 & 7;
    float v[8];
    #pragma unroll
    for (int j = 0; j < 8; ++j) v[j] = We[(size_t)(ks * 32 + quad * 8 + j) * Uv + nj * 16 + l4];
    uint4 o;
    o.x = pack2(f2bf(v[0]), f2bf(v[1])); o.y = pack2(f2bf(v[2]), f2bf(v[3]));
    o.z = pack2(f2bf(v[4]), f2bf(v[5])); o.w = pack2(f2bf(v[6]), f2bf(v[7]));
    *(uint4*)(WeF + (size_t)f2 * 512 + lane * 8) = o;
  } else {
    const int base = (bx - 105) * 2048 + tid * 8;  // 16512 floats total, 8 per thread
    if (base < 16512) {
      float4 z = {0.f, 0.f, 0.f, 0.f};
      *(float4*)(zeroRegion + base) = z;
      *(float4*)(zeroRegion + base + 4) = z;
    }
  }
}

// ================= main fused kernel (incl. finish) =================
__global__ __launch_bounds__(256, 4) void main_kernel(
    const float* __restrict__ memory, const unsigned short* __restrict__ WmF,
    const unsigned short* __restrict__ WeF, const unsigned short* __restrict__ W3F,
    const float* __restrict__ qe, const float* __restrict__ state,
    const float* __restrict__ prev_cum, const float* __restrict__ bm,
    const float* __restrict__ va,
    float* __restrict__ P0, float* __restrict__ P1, float* __restrict__ Ssg,
    int* __restrict__ cnt, float* __restrict__ out) {
  const int tid = threadIdx.x;
  const int lane = tid & 63, wid = tid >> 6;
  const int l4 = lane & 15, quad = lane >> 4;
  const int wt = wid >> 1, wu = wid & 1;
  const int b = blockIdx.y, t0 = blockIdx.x * 64;

  __shared__ float sState[124];
  __shared__ float sPc[64];
  __shared__ float sBm[128];
  __shared__ float sVa[128];
  __shared__ float sSg[64];
  __shared__ float blkP0[128], blkP1[128];
  __shared__ float blkSsg;
  __shared__ int sDone;
  __shared__ __align__(16) unsigned short sS[64 * 136];  // stride 136: 2-way LDS conflicts only

  for (int i = tid; i < 124; i += 256) {
    int t = t0 - 30 + i;
    sState[i] = (t >= 0 && t < Tv) ? state[b * Tv + t] : 0.0f;
  }
  if (tid < 64) sPc[tid] = prev_cum[b * Tv + t0 + tid];
  if (tid < 128) { sBm[tid] = bm[tid]; sVa[tid] = va[tid]; blkP0[tid] = 0.0f; blkP1[tid] = 0.0f; }
  if (tid == 0) blkSsg = 0.0f;

  // ---- phase 1: pm GEMM with 2-deep register prefetch ----
  f32x4 acc[2][4];
  #pragma unroll
  for (int ti = 0; ti < 2; ++ti)
    #pragma unroll
    for (int uj = 0; uj < 4; ++uj) acc[ti][uj] = (f32x4){0.f, 0.f, 0.f, 0.f};

  const float* aPtr = memory + ((size_t)b * Tv + t0 + wt * 32 + l4) * Mv + quad * 8;
  const unsigned short* bPtr = WmF + (size_t)(wu * 4) * 512 + lane * 8;

  float4 Abuf[2][4];
  uint4  Bbuf[2][4];
  Abuf[0][0] = *(const float4*)(aPtr);
  Abuf[0][1] = *(const float4*)(aPtr + 4);
  Abuf[0][2] = *(const float4*)(aPtr + (size_t)16 * Mv);
  Abuf[0][3] = *(const float4*)(aPtr + (size_t)16 * Mv + 4);
  #pragma unroll
  for (int j = 0; j < 4; ++j) Bbuf[0][j] = *(const uint4*)(bPtr + (size_t)j * 512);

  #pragma unroll
  for (int kc = 0; kc < 16; ++kc) {
    const int cur = kc & 1, nxt = cur ^ 1;
    if (kc < 15) {
      const float* ap = aPtr + (kc + 1) * 32;
      Abuf[nxt][0] = *(const float4*)(ap);
      Abuf[nxt][1] = *(const float4*)(ap + 4);
      Abuf[nxt][2] = *(const float4*)(ap + (size_t)16 * Mv);
      Abuf[nxt][3] = *(const float4*)(ap + (size_t)16 * Mv + 4);
      #pragma unroll
      for (int j = 0; j < 4; ++j)
        Bbuf[nxt][j] = *(const uint4*)(bPtr + (size_t)((kc + 1) * 8 + j) * 512);
    }
    bf16x8 af0, af1;
    af0[0] = (__bf16)Abuf[cur][0].x; af0[1] = (__bf16)Abuf[cur][0].y;
    af0[2] = (__bf16)Abuf[cur][0].z; af0[3] = (__bf16)Abuf[cur][0].w;
    af0[4] = (__bf16)Abuf[cur][1].x; af0[5] = (__bf16)Abuf[cur][1].y;
    af0[6] = (__bf16)Abuf[cur][1].z; af0[7] = (__bf16)Abuf[cur][1].w;
    af1[0] = (__bf16)Abuf[cur][2].x; af1[1] = (__bf16)Abuf[cur][2].y;
    af1[2] = (__bf16)Abuf[cur][2].z; af1[3] = (__bf16)Abuf[cur][2].w;
    af1[4] = (__bf16)Abuf[cur][3].x; af1[5] = (__bf16)Abuf[cur][3].y;
    af1[6] = (__bf16)Abuf[cur][3].z; af1[7] = (__bf16)Abuf[cur][3].w;
    #pragma unroll
    for (int uj = 0; uj < 4; ++uj) {
      U4BF bb; bb.u = Bbuf[cur][uj];
      acc[0][uj] = MFMA(af0, bb.b, acc[0][uj]);
      acc[1][uj] = MFMA(af1, bb.b, acc[1][uj]);
    }
  }

  // early independent loads for phase 2 (overlap with LDS writes)
  float qv[8];
  U4BF w3[8];
  #pragma unroll
  for (int nj = 0; nj < 8; ++nj) {
    qv[nj] = qe[b * Uv + nj * 16 + l4];
    w3[nj].u = *(const uint4*)(W3F + (size_t)nj * 512 + lane * 8);
  }

  // pm (bf16) -> LDS; C layout: col=lane&15, row=quad*4+reg
  #pragma unroll
  for (int ti = 0; ti < 2; ++ti) {
    const int rowb = wt * 32 + ti * 16 + quad * 4;
    #pragma unroll
    for (int uj = 0; uj < 4; ++uj) {
      const int col = wu * 64 + uj * 16 + l4;
      #pragma unroll
      for (int r = 0; r < 4; ++r) sS[(rowb + r) * 136 + col] = f2bf(acc[ti][uj][r]);
    }
  }
  __syncthreads();

  // ---- phase 2: e2 = pm@We + S2@W3 + qe[b] ----
  f32x4 e[8];
  #pragma unroll
  for (int nj = 0; nj < 8; ++nj) e[nj] = (f32x4){qv[nj], qv[nj], qv[nj], qv[nj]};
  bf16x8 a2f;
  #pragma unroll
  for (int j = 0; j < 8; ++j) {
    int k = quad * 8 + j;
    float v = (k < 31) ? sState[(wid * 16 + l4) + 2 * k] : 0.0f;
    a2f[j] = (__bf16)v;
  }
  #pragma unroll
  for (int nj = 0; nj < 8; ++nj) e[nj] = MFMA(a2f, w3[nj].b, e[nj]);
  #pragma unroll
  for (int ks = 0; ks < 4; ++ks) {
    U4BF au;
    au.u = *(const uint4*)&sS[(wid * 16 + l4) * 136 + ks * 32 + quad * 8];
    #pragma unroll
    for (int nj = 0; nj < 8; ++nj) {
      U4BF bb; bb.u = *(const uint4*)(WeF + (size_t)(ks * 8 + nj) * 512 + lane * 8);
      e[nj] = MFMA(au.b, bb.b, e[nj]);
    }
  }
  float p[4] = {0.f, 0.f, 0.f, 0.f};
  #pragma unroll
  for (int nj = 0; nj < 8; ++nj) {
    float vav = sVa[nj * 16 + l4];
    #pragma unroll
    for (int r = 0; r < 4; ++r) p[r] = fmaf(vav, fast_tanh(e[nj][r]), p[r]);
  }
  #pragma unroll
  for (int off = 1; off <= 8; off <<= 1) {
    #pragma unroll
    for (int r = 0; r < 4; ++r) p[r] += __shfl_xor(p[r], off, 64);
  }
  float sgsum = 0.f;
  float sgv4[4];
  #pragma unroll
  for (int r = 0; r < 4; ++r) {
    sgv4[r] = 1.0f / (1.0f + __expf(-p[r]));
    sgsum += sgv4[r];
  }
  if (l4 == 0) {
    #pragma unroll
    for (int r = 0; r < 4; ++r) sSg[wid * 16 + quad * 4 + r] = sgv4[r];
    atomicAdd(&blkSsg, sgsum);
  }
  __syncthreads();

  // ---- phase 3: P0/P1 accumulation ----
  float sgl[8], pcl[8];
  #pragma unroll
  for (int ti = 0; ti < 2; ++ti)
    #pragma unroll
    for (int r = 0; r < 4; ++r) {
      int row = wt * 32 + ti * 16 + quad * 4 + r;
      sgl[ti * 4 + r] = sSg[row];
      pcl[ti * 4 + r] = sPc[row];
    }
  #pragma unroll
  for (int uj = 0; uj < 4; ++uj) {
    const int col = wu * 64 + uj * 16 + l4;
    const float bmv = sBm[col];
    float c0 = 0.f, c1 = 0.f;
    #pragma unroll
    for (int ti = 0; ti < 2; ++ti)
      #pragma unroll
      for (int r = 0; r < 4; ++r) {
        float pmv = acc[ti][uj][r] + bmv;
        c0 = fmaf(pcl[ti * 4 + r], pmv, c0);
        c1 = fmaf(sgl[ti * 4 + r], pmv, c1);
      }
    c0 += __shfl_xor(c0, 16, 64); c0 += __shfl_xor(c0, 32, 64);
    c1 += __shfl_xor(c1, 16, 64); c1 += __shfl_xor(c1, 32, 64);
    if (quad == 0) {
      atomicAdd(&blkP0[col], c0);
      atomicAdd(&blkP1[col], c1);
    }
  }
  __syncthreads();
  if (tid < 128) {
    unsafeAtomicAdd(&P0[b * Uv + tid], blkP0[tid]);
    unsafeAtomicAdd(&P1[b * Uv + tid], blkP1[tid]);
  }
  if (tid == 0) unsafeAtomicAdd(&Ssg[b], blkSsg);
  __syncthreads();  // drains vmcnt in every wave -> block's atomics globally performed

  // ---- fused finish: last block per batch writes the output ----
  if (tid == 0) {
    __threadfence();
    sDone = __hip_atomic_fetch_add(&cnt[b], 1, __ATOMIC_ACQ_REL, __HIP_MEMORY_SCOPE_AGENT);
  }
  __syncthreads();
  if (sDone == 31) {
    __threadfence();
    if (tid < 128) {
      float p0 = __hip_atomic_load(&P0[b * Uv + tid], __ATOMIC_ACQUIRE, __HIP_MEMORY_SCOPE_AGENT);
      float p1 = __hip_atomic_load(&P1[b * Uv + tid], __ATOMIC_ACQUIRE, __HIP_MEMORY_SCOPE_AGENT);
      float ss = __hip_atomic_load(&Ssg[b], __ATOMIC_ACQUIRE, __HIP_MEMORY_SCOPE_AGENT);
      out[b * Uv + tid] = p0 + p1 / ss;
    }
  }
}

extern "C" void kernel_launch(void* const* d_in, const int* in_sizes, int n_in,
                              void* d_out, int out_size, void* d_ws, size_t ws_size,
                              hipStream_t stream) {
  (void)in_sizes; (void)n_in; (void)out_size; (void)ws_size;
  const float* query    = (const float*)d_in[0];
  const float* state    = (const float*)d_in[1];
  const float* prev_cum = (const float*)d_in[2];
  const float* memory   = (const float*)d_in[3];
  const float* Wq       = (const float*)d_in[4];
  const float* bq       = (const float*)d_in[5];
  const float* Wm       = (const float*)d_in[6];
  const float* bm       = (const float*)d_in[7];
  const float* Wl       = (const float*)d_in[8];
  const float* bl       = (const float*)d_in[9];
  const float* We       = (const float*)d_in[10];
  const float* be       = (const float*)d_in[11];
  const float* va       = (const float*)d_in[12];
  const float* conv_w   = (const float*)d_in[13];
  const float* conv_b   = (const float*)d_in[14];

  float* ws = (float*)d_ws;
  float* P0  = ws;                          // 8192
  float* P1  = ws + 8192;                   // 8192
  float* Ssg = ws + 16384;                  // 64
  int*   cnt = (int*)(ws + 16448);          // 64  (zeroed with region above)
  float* qe  = ws + 16512;                  // 8192
  unsigned short* W3F = (unsigned short*)(ws + 24704);  // 4096 bf16
  unsigned short* WmF = (unsigned short*)(ws + 26752);  // 65536 bf16
  unsigned short* WeF = (unsigned short*)(ws + 59520);  // 16384 bf16
  // total 67712 floats = 271 KB

  prep_kernel<<<114, 256, 0, stream>>>(query, Wq, bq, Wl, bl, conv_w, conv_b,
                                       bm, be, We, Wm, qe, W3F, WmF, WeF, ws);
  main_kernel<<<dim3(Tv / 64, Bv), 256, 0, stream>>>(
      memory, WmF, WeF, W3F, qe, state, prev_cum, bm, va, P0, P1, Ssg, cnt,
      (float*)d_out);
}

// Round 4
// 661.770 us; speedup vs baseline: 1.0164x; 1.0164x over previous
//
#include <hip/hip_runtime.h>

#define Bv 64
#define Tv 2048
#define Hv 1024
#define Uv 128
#define Mv 512

typedef __bf16 bf16x8 __attribute__((ext_vector_type(8)));
typedef float f32x4 __attribute__((ext_vector_type(4)));
union U4BF { uint4 u; bf16x8 b; };
#define MFMA(a, b, c) __builtin_amdgcn_mfma_f32_16x16x32_bf16((a), (b), (c), 0, 0, 0)

__device__ __forceinline__ unsigned short f2bf(float f) {
  __bf16 h = (__bf16)f;
  return __builtin_bit_cast(unsigned short, h);
}
__device__ __forceinline__ unsigned int pack2(unsigned short lo, unsigned short hi) {
  return (unsigned int)lo | ((unsigned int)hi << 16);
}
__device__ __forceinline__ float fast_tanh(float x) {
  x = fminf(fmaxf(x, -15.0f), 15.0f);
  float e = __expf(2.0f * x);
  return (e - 1.0f) / (e + 1.0f);
}

// ================= prep: one launch does everything =================
// bx in [0,64):   qe[b,n] = (query[b]@Wq + bq + bias2 + bm)@We + be
// bx == 64:       W2 = conv-fold(Wl), W3 = W2@We, pack W3F
// bx in [65,97):  pack WmF (4 frags/block)
// bx in [97,105): pack WeF (4 frags/block)
// bx in [105,114): zero P0/P1/Ssg/cnt (first 16512 floats of ws)
__global__ __launch_bounds__(256) void prep_kernel(
    const float* __restrict__ query, const float* __restrict__ Wq,
    const float* __restrict__ bq, const float* __restrict__ Wl,
    const float* __restrict__ bl, const float* __restrict__ conv_w,
    const float* __restrict__ conv_b, const float* __restrict__ bm,
    const float* __restrict__ be, const float* __restrict__ We,
    const float* __restrict__ Wm,
    float* __restrict__ qe, unsigned short* __restrict__ W3F,
    unsigned short* __restrict__ WmF, unsigned short* __restrict__ WeF,
    float* __restrict__ zeroRegion) {
  const int bx = blockIdx.x, tid = threadIdx.x;
  if (bx < 64) {
    const int b = bx;
    __shared__ float part[256];
    __shared__ float svec[128];
    const int u = tid & 127, half = tid >> 7;
    float acc = 0.0f;
    const float* q  = query + b * Hv + half * 512;
    const float* wq = Wq + (size_t)(half * 512) * Uv + u;
    for (int h = 0; h < 512; ++h) acc = fmaf(q[h], wq[(size_t)h * Uv], acc);
    part[tid] = acc;
    __syncthreads();
    if (tid < 128) {
      float pq = part[tid] + part[tid + 128] + bq[tid];
      float b2 = bl[tid];
      #pragma unroll
      for (int f = 0; f < 32; ++f) b2 = fmaf(conv_b[f], Wl[f * Uv + tid], b2);
      svec[tid] = pq + b2 + bm[tid];
    }
    __syncthreads();
    const int n = tid & 127;
    float acc2 = 0.0f;
    const float* we = We + (size_t)(half * 64) * Uv + n;
    for (int uu = 0; uu < 64; ++uu) acc2 = fmaf(svec[half * 64 + uu], we[(size_t)uu * Uv], acc2);
    part[tid] = acc2;
    __syncthreads();
    if (tid < 128) qe[b * Uv + tid] = part[tid] + part[tid + 128] + be[tid];
  } else if (bx == 64) {
    __shared__ float sW2[31 * 128];
    __shared__ float sW3[32 * 128];
    for (int idx = tid; idx < 31 * 128; idx += 256) {
      int k = idx >> 7, uu = idx & 127;
      float a = 0.0f;
      #pragma unroll
      for (int f = 0; f < 32; ++f) a = fmaf(conv_w[f * 31 + k], Wl[f * Uv + uu], a);
      sW2[idx] = a;
    }
    __syncthreads();
    for (int idx = tid; idx < 32 * 128; idx += 256) {
      int k = idx >> 7, n = idx & 127;
      float a = 0.0f;
      if (k < 31) {
        for (int uu = 0; uu < 128; ++uu) a = fmaf(sW2[k * 128 + uu], We[(size_t)uu * Uv + n], a);
      }
      sW3[idx] = a;
    }
    __syncthreads();
    for (int s = tid; s < 512; s += 256) {
      int nj = s >> 6, lane = s & 63, quad = lane >> 4, l4 = lane & 15;
      float v[8];
      #pragma unroll
      for (int j = 0; j < 8; ++j) v[j] = sW3[(quad * 8 + j) * 128 + nj * 16 + l4];
      uint4 o;
      o.x = pack2(f2bf(v[0]), f2bf(v[1])); o.y = pack2(f2bf(v[2]), f2bf(v[3]));
      o.z = pack2(f2bf(v[4]), f2bf(v[5])); o.w = pack2(f2bf(v[6]), f2bf(v[7]));
      *(uint4*)(W3F + (size_t)nj * 512 + lane * 8) = o;
    }
  } else if (bx < 97) {
    const int fid = (bx - 65) * 4 + (tid >> 6);
    const int lane = tid & 63, quad = lane >> 4, l4 = lane & 15;
    const int kc = fid >> 3, uj = fid & 7;
    float v[8];
    #pragma unroll
    for (int j = 0; j < 8; ++j) v[j] = Wm[(size_t)(kc * 32 + quad * 8 + j) * Uv + uj * 16 + l4];
    uint4 o;
    o.x = pack2(f2bf(v[0]), f2bf(v[1])); o.y = pack2(f2bf(v[2]), f2bf(v[3]));
    o.z = pack2(f2bf(v[4]), f2bf(v[5])); o.w = pack2(f2bf(v[6]), f2bf(v[7]));
    *(uint4*)(WmF + (size_t)fid * 512 + lane * 8) = o;
  } else if (bx < 105) {
    const int f2 = (bx - 97) * 4 + (tid >> 6);
    const int lane = tid & 63, quad = lane >> 4, l4 = lane & 15;
    const int ks = f2 >> 3, nj = f2 & 7;
    float v[8];
    #pragma unroll
    for (int j = 0; j < 8; ++j) v[j] = We[(size_t)(ks * 32 + quad * 8 + j) * Uv + nj * 16 + l4];
    uint4 o;
    o.x = pack2(f2bf(v[0]), f2bf(v[1])); o.y = pack2(f2bf(v[2]), f2bf(v[3]));
    o.z = pack2(f2bf(v[4]), f2bf(v[5])); o.w = pack2(f2bf(v[6]), f2bf(v[7]));
    *(uint4*)(WeF + (size_t)f2 * 512 + lane * 8) = o;
  } else {
    const int base = (bx - 105) * 2048 + tid * 8;  // 16512 floats total
    if (base < 16512) {
      float4 z = {0.f, 0.f, 0.f, 0.f};
      *(float4*)(zeroRegion + base) = z;
      *(float4*)(zeroRegion + base + 4) = z;
    }
  }
}

// ================= main fused kernel (incl. finish) =================
// Wave wid owns t-rows [wid*16, wid*16+16) x ALL 128 u  -> A read ONCE per block.
__global__ __launch_bounds__(256) void main_kernel(
    const float* __restrict__ memory, const unsigned short* __restrict__ WmF,
    const unsigned short* __restrict__ WeF, const unsigned short* __restrict__ W3F,
    const float* __restrict__ qe, const float* __restrict__ state,
    const float* __restrict__ prev_cum, const float* __restrict__ bm,
    const float* __restrict__ va,
    float* __restrict__ P0, float* __restrict__ P1, float* __restrict__ Ssg,
    int* __restrict__ cnt, float* __restrict__ out) {
  const int tid = threadIdx.x;
  const int lane = tid & 63, wid = tid >> 6;
  const int l4 = lane & 15, quad = lane >> 4;
  const int b = blockIdx.y, t0 = blockIdx.x * 64;

  __shared__ float sState[124];
  __shared__ float sPc[64];
  __shared__ float sBm[128];
  __shared__ float sVa[128];
  __shared__ float sSg[64];
  __shared__ float blkP0[128], blkP1[128];
  __shared__ float blkSsg;
  __shared__ int sDone;
  __shared__ __align__(16) unsigned short sS[64 * 136];  // stride 136

  for (int i = tid; i < 124; i += 256) {
    int t = t0 - 30 + i;
    sState[i] = (t >= 0 && t < Tv) ? state[b * Tv + t] : 0.0f;
  }
  if (tid < 64) sPc[tid] = prev_cum[b * Tv + t0 + tid];
  if (tid < 128) { sBm[tid] = bm[tid]; sVa[tid] = va[tid]; blkP0[tid] = 0.0f; blkP1[tid] = 0.0f; }
  if (tid == 0) blkSsg = 0.0f;

  // ---- phase 1: pm GEMM. A-frag rows wid*16+l4, k = quad*8+j; 8 u-tiles ----
  f32x4 acc[8];
  #pragma unroll
  for (int uj = 0; uj < 8; ++uj) acc[uj] = (f32x4){0.f, 0.f, 0.f, 0.f};

  const float* aPtr = memory + ((size_t)b * Tv + t0 + wid * 16 + l4) * Mv + quad * 8;
  const unsigned short* bPtr = WmF + lane * 8;

  for (int kc = 0; kc < 16; ++kc) {
    float4 a0 = *(const float4*)(aPtr + kc * 32);
    float4 a1 = *(const float4*)(aPtr + kc * 32 + 4);
    U4BF bf[8];
    #pragma unroll
    for (int uj = 0; uj < 8; ++uj)
      bf[uj].u = *(const uint4*)(bPtr + (size_t)(kc * 8 + uj) * 512);
    bf16x8 af;
    af[0] = (__bf16)a0.x; af[1] = (__bf16)a0.y; af[2] = (__bf16)a0.z; af[3] = (__bf16)a0.w;
    af[4] = (__bf16)a1.x; af[5] = (__bf16)a1.y; af[6] = (__bf16)a1.z; af[7] = (__bf16)a1.w;
    #pragma unroll
    for (int uj = 0; uj < 8; ++uj) acc[uj] = MFMA(af, bf[uj].b, acc[uj]);
  }

  // early independent loads for phase 2
  float qv[8];
  U4BF w3[8];
  #pragma unroll
  for (int nj = 0; nj < 8; ++nj) {
    qv[nj] = qe[b * Uv + nj * 16 + l4];
    w3[nj].u = *(const uint4*)(W3F + (size_t)nj * 512 + lane * 8);
  }

  // pm (bf16) -> LDS; C layout: col=l4, row=quad*4+r within 16x16 tile
  #pragma unroll
  for (int uj = 0; uj < 8; ++uj) {
    const int rowb = wid * 16 + quad * 4;
    const int col = uj * 16 + l4;
    #pragma unroll
    for (int r = 0; r < 4; ++r) sS[(rowb + r) * 136 + col] = f2bf(acc[uj][r]);
  }
  __syncthreads();

  // ---- phase 2: e2 = pm@We + S2@W3 + qe[b]; wave wid owns t-rows wid*16..+16 ----
  f32x4 e[8];
  #pragma unroll
  for (int nj = 0; nj < 8; ++nj) e[nj] = (f32x4){qv[nj], qv[nj], qv[nj], qv[nj]};
  bf16x8 a2f;
  #pragma unroll
  for (int j = 0; j < 8; ++j) {
    int k = quad * 8 + j;
    float v = (k < 31) ? sState[(wid * 16 + l4) + 2 * k] : 0.0f;
    a2f[j] = (__bf16)v;
  }
  #pragma unroll
  for (int nj = 0; nj < 8; ++nj) e[nj] = MFMA(a2f, w3[nj].b, e[nj]);
  #pragma unroll
  for (int ks = 0; ks < 4; ++ks) {
    U4BF au;
    au.u = *(const uint4*)&sS[(wid * 16 + l4) * 136 + ks * 32 + quad * 8];
    #pragma unroll
    for (int nj = 0; nj < 8; ++nj) {
      U4BF bb; bb.u = *(const uint4*)(WeF + (size_t)(ks * 8 + nj) * 512 + lane * 8);
      e[nj] = MFMA(au.b, bb.b, e[nj]);
    }
  }
  float p[4] = {0.f, 0.f, 0.f, 0.f};
  #pragma unroll
  for (int nj = 0; nj < 8; ++nj) {
    float vav = sVa[nj * 16 + l4];
    #pragma unroll
    for (int r = 0; r < 4; ++r) p[r] = fmaf(vav, fast_tanh(e[nj][r]), p[r]);
  }
  #pragma unroll
  for (int off = 1; off <= 8; off <<= 1) {
    #pragma unroll
    for (int r = 0; r < 4; ++r) p[r] += __shfl_xor(p[r], off, 64);
  }
  float sgsum = 0.f;
  float sgv4[4];
  #pragma unroll
  for (int r = 0; r < 4; ++r) {
    sgv4[r] = 1.0f / (1.0f + __expf(-p[r]));
    sgsum += sgv4[r];
  }
  if (l4 == 0) {
    #pragma unroll
    for (int r = 0; r < 4; ++r) sSg[wid * 16 + quad * 4 + r] = sgv4[r];
    atomicAdd(&blkSsg, sgsum);
  }
  __syncthreads();

  // ---- phase 3: P0/P1 accumulation (rows wid*16+quad*4+r, cols uj*16+l4) ----
  float sgl[4], pcl[4];
  #pragma unroll
  for (int r = 0; r < 4; ++r) {
    int row = wid * 16 + quad * 4 + r;
    sgl[r] = sSg[row];
    pcl[r] = sPc[row];
  }
  #pragma unroll
  for (int uj = 0; uj < 8; ++uj) {
    const int col = uj * 16 + l4;
    const float bmv = sBm[col];
    float c0 = 0.f, c1 = 0.f;
    #pragma unroll
    for (int r = 0; r < 4; ++r) {
      float pmv = acc[uj][r] + bmv;
      c0 = fmaf(pcl[r], pmv, c0);
      c1 = fmaf(sgl[r], pmv, c1);
    }
    c0 += __shfl_xor(c0, 16, 64); c0 += __shfl_xor(c0, 32, 64);
    c1 += __shfl_xor(c1, 16, 64); c1 += __shfl_xor(c1, 32, 64);
    if (quad == 0) {
      atomicAdd(&blkP0[col], c0);
      atomicAdd(&blkP1[col], c1);
    }
  }
  __syncthreads();
  if (tid < 128) {
    unsafeAtomicAdd(&P0[b * Uv + tid], blkP0[tid]);
    unsafeAtomicAdd(&P1[b * Uv + tid], blkP1[tid]);
  }
  if (tid == 0) unsafeAtomicAdd(&Ssg[b], blkSsg);
  __syncthreads();

  // ---- fused finish: last block per batch writes the output ----
  if (tid == 0) {
    __threadfence();
    sDone = __hip_atomic_fetch_add(&cnt[b], 1, __ATOMIC_ACQ_REL, __HIP_MEMORY_SCOPE_AGENT);
  }
  __syncthreads();
  if (sDone == 31) {
    __threadfence();
    if (tid < 128) {
      float p0 = __hip_atomic_load(&P0[b * Uv + tid], __ATOMIC_ACQUIRE, __HIP_MEMORY_SCOPE_AGENT);
      float p1 = __hip_atomic_load(&P1[b * Uv + tid], __ATOMIC_ACQUIRE, __HIP_MEMORY_SCOPE_AGENT);
      float ss = __hip_atomic_load(&Ssg[b], __ATOMIC_ACQUIRE, __HIP_MEMORY_SCOPE_AGENT);
      out[b * Uv + tid] = p0 + p1 / ss;
    }
  }
}

extern "C" void kernel_launch(void* const* d_in, const int* in_sizes, int n_in,
                              void* d_out, int out_size, void* d_ws, size_t ws_size,
                              hipStream_t stream) {
  (void)in_sizes; (void)n_in; (void)out_size; (void)ws_size;
  const float* query    = (const float*)d_in[0];
  const float* state    = (const float*)d_in[1];
  const float* prev_cum = (const float*)d_in[2];
  const float* memory   = (const float*)d_in[3];
  const float* Wq       = (const float*)d_in[4];
  const float* bq       = (const float*)d_in[5];
  const float* Wm       = (const float*)d_in[6];
  const float* bm       = (const float*)d_in[7];
  const float* Wl       = (const float*)d_in[8];
  const float* bl       = (const float*)d_in[9];
  const float* We       = (const float*)d_in[10];
  const float* be       = (const float*)d_in[11];
  const float* va       = (const float*)d_in[12];
  const float* conv_w   = (const float*)d_in[13];
  const float* conv_b   = (const float*)d_in[14];

  float* ws = (float*)d_ws;
  float* P0  = ws;                          // 8192
  float* P1  = ws + 8192;                   // 8192
  float* Ssg = ws + 16384;                  // 64
  int*   cnt = (int*)(ws + 16448);          // 64
  float* qe  = ws + 16512;                  // 8192
  unsigned short* W3F = (unsigned short*)(ws + 24704);  // 4096 bf16
  unsigned short* WmF = (unsigned short*)(ws + 26752);  // 65536 bf16
  unsigned short* WeF = (unsigned short*)(ws + 59520);  // 16384 bf16

  prep_kernel<<<114, 256, 0, stream>>>(query, Wq, bq, Wl, bl, conv_w, conv_b,
                                       bm, be, We, Wm, qe, W3F, WmF, WeF, ws);
  main_kernel<<<dim3(Tv / 64, Bv), 256, 0, stream>>>(
      memory, WmF, WeF, W3F, qe, state, prev_cum, bm, va, P0, P1, Ssg, cnt,
      (float*)d_out);
}